// Round 3
// baseline (427.835 us; speedup 1.0000x reference)
//
#include <hip/hip_runtime.h>

// DepthToSpace DCR, block_size=2.
// in:  (16, 256, 128, 128) f32
// out: (16,  64, 256, 256) f32
// out[b, c, 2h+j, 2w+r] = in[b, (2j+r)*64 + c, h, w]
//
// v4: v2's wide-load structure, with REGULAR cached accesses (v2's regression
// was entirely the nontemporal hints; v3 proved cached is right but used 8B
// loads). Each thread handles both output rows (j=0,1) of one (b,c,h,w4):
//   - 4 float4 loads, one per channel stream {c, c+64, c+128, c+192}.
//     Per wave: lanes 0-31 cover input row h, lanes 32-63 row h+1 (adjacent
//     in memory) -> each load instruction covers one contiguous 1KiB block.
//   - 4 float4 stores: rows 2h and 2h+1 (lanes 0-31) / 2h+2, 2h+3 (32-63),
//     every output row covered completely, all full-line writes.
// 4.2M threads: half of v3's count -> half the index math per byte moved.

constexpr int B  = 16;
constexpr int D  = 256;
constexpr int H  = 128;
constexpr int W  = 128;
constexpr int BS = 2;
constexpr int C  = D / (BS * BS);   // 64
constexpr int H2 = H * BS;          // 256
constexpr int W2 = W * BS;          // 256

typedef float f4 __attribute__((ext_vector_type(4)));

__global__ __launch_bounds__(256) void d2s_kernel(const float* __restrict__ in,
                                                  float* __restrict__ out) {
    const int tid = blockIdx.x * blockDim.x + threadIdx.x;
    // thread layout: [b][c][h][w4], w4 in [0,32) selecting 4 input w's
    const int w4 = tid & 31;                // W/4 = 32 float4 groups per input row
    const int h  = (tid >> 5) & (H - 1);    // 128
    const int c  = (tid >> 12) & (C - 1);   // 64
    const int b  = tid >> 18;

    // float4-granular indices (all buffers 16B aligned, W % 4 == 0)
    const size_t in_base = (((size_t)((b * D + c) * H + h)) * W >> 2) + w4;
    constexpr size_t CH4 = (size_t)C * H * W / 4;   // one channel-group in f4 units

    const f4* __restrict__ ip = reinterpret_cast<const f4*>(in);
    const f4 a0 = ip[in_base + 0 * CH4];   // ch c        (j=0, r=0)
    const f4 a1 = ip[in_base + 1 * CH4];   // ch c+64     (j=0, r=1)
    const f4 a2 = ip[in_base + 2 * CH4];   // ch c+128    (j=1, r=0)
    const f4 a3 = ip[in_base + 3 * CH4];   // ch c+192    (j=1, r=1)

    // output: row 2h gets interleave(a0,a1), row 2h+1 gets interleave(a2,a3)
    const size_t out_row0 = ((size_t)((b * C + c) * H2 + 2 * h)) * (W2 / 4) + (w4 << 1);
    f4* __restrict__ op = reinterpret_cast<f4*>(out);

    op[out_row0 + 0]            = f4{a0.x, a1.x, a0.y, a1.y};   // row 2h, first half
    op[out_row0 + 1]            = f4{a0.z, a1.z, a0.w, a1.w};   // row 2h, second half
    op[out_row0 + (W2 / 4) + 0] = f4{a2.x, a3.x, a2.y, a3.y};   // row 2h+1
    op[out_row0 + (W2 / 4) + 1] = f4{a2.z, a3.z, a2.w, a3.w};
}

extern "C" void kernel_launch(void* const* d_in, const int* in_sizes, int n_in,
                              void* d_out, int out_size, void* d_ws, size_t ws_size,
                              hipStream_t stream) {
    const float* in = (const float*)d_in[0];
    float* out = (float*)d_out;

    // total threads = B*C*H*(W/4) = 16*64*128*32 = 4,194,304
    const int total_threads = B * C * H * (W / 4);
    const int block = 256;
    const int grid = total_threads / block;   // 16384

    d2s_kernel<<<grid, block, 0, stream>>>(in, out);
}